// Round 8
// baseline (912.804 us; speedup 1.0000x reference)
//
#include <hip/hip_runtime.h>

#define CC 256
#define HH 256
#define WW 256
#define HWV 65536
#define NN 4096
#define CG 16      // channels (planes) per fused-gather block
#define SROWS 19   // staged rows: 16-row band + 2 above + 1 below

using u64 = unsigned long long;
using u32 = unsigned int;

__device__ __forceinline__ u32 lbound(const u32* __restrict__ a, u32 n, u32 key) {
    u32 lo = 0, hi = n;
    while (lo < hi) { u32 mid = (lo + hi) >> 1; if (a[mid] < key) lo = mid + 1; else hi = mid; }
    return lo;
}

// ---------------------------------------------------------------------------
// K1: 48-bit sortable keys: (monotone(float) << 16) | (0xFFFF - pix).
// Distinct per pixel; descending key order == lax.top_k order.
__global__ void build_keys_k(const float* __restrict__ pm, const int* __restrict__ em,
                             u64* __restrict__ keys) {
    int i = blockIdx.x * blockDim.x + threadIdx.x;   // b*65536 + pix
    float f = (em[i] == 1) ? -fabsf(pm[i]) : -1e30f;
    u32 u = __float_as_uint(f);
    u32 k = (u & 0x80000000u) ? ~u : (u | 0x80000000u);
    u32 pix = (u32)i & 0xFFFFu;
    keys[i] = ((u64)k << 16) | (u64)(0xFFFFu - pix);
}

// ---------------------------------------------------------------------------
// K2 (fused): blocks 0-7 = per-batch exact top-k radix-select + desc bitonic
// + spatial re-sort; blocks 8-15 = spatial sort of point_coords.
__global__ __launch_bounds__(1024) void topk_sortpc_k(const u64* __restrict__ keys,
                                                      const float* __restrict__ pc,
                                                      u32* __restrict__ stash,
                                                      u32* __restrict__ pixSorted,
                                                      u32* __restrict__ pcSorted) {
    __shared__ u32 hist[256];
    __shared__ u32 scanb[256];
    __shared__ u64 sel[NN];
    __shared__ u32 s_digit, s_rem, s_cnt;
    const int t = threadIdx.x;
    if (blockIdx.x < 8) {
        const int b = blockIdx.x;
        const u64* kb = keys + (size_t)b * HWV;
        u64 prefix = 0ULL;
        u32 remaining = NN;
        for (int r = 0; r < 6; ++r) {
            int shift = 40 - 8 * r;
            if (t < 256) hist[t] = 0u;
            __syncthreads();
            for (int i = t; i < HWV; i += 1024) {
                u64 K = kb[i];
                if ((K >> (shift + 8)) == prefix)
                    atomicAdd(&hist[(u32)((K >> shift) & 0xFFULL)], 1u);
            }
            __syncthreads();
            if (t < 256) scanb[t] = hist[t];
            __syncthreads();
            for (int off = 1; off < 256; off <<= 1) {   // suffix sums
                u32 v = 0;
                if (t < 256) { v = scanb[t]; if (t + off < 256) v += scanb[t + off]; }
                __syncthreads();
                if (t < 256) scanb[t] = v;
                __syncthreads();
            }
            if (t < 256) {
                u32 ge = scanb[t];
                u32 gt = (t < 255) ? scanb[t + 1] : 0u;
                if (ge >= remaining && gt < remaining) { s_digit = (u32)t; s_rem = remaining - gt; }
            }
            __syncthreads();
            prefix = (prefix << 8) | (u64)s_digit;
            remaining = s_rem;
            __syncthreads();
        }
        if (t == 0) s_cnt = 0u;
        __syncthreads();
        for (int i = t; i < HWV; i += 1024) {
            u64 K = kb[i];
            if (K >= prefix) { u32 p = atomicAdd(&s_cnt, 1u); sel[p] = K; }
        }
        __syncthreads();
        for (int k = 2; k <= NN; k <<= 1) {           // bitonic desc
            for (int j = k >> 1; j > 0; j >>= 1) {
                for (int i = t; i < NN; i += 1024) {
                    int l = i ^ j;
                    if (l > i) {
                        u64 a = sel[i], c = sel[l];
                        bool asc = ((i & k) == 0);
                        if ((a < c) == asc) { sel[i] = c; sel[l] = a; }
                    }
                }
                __syncthreads();
            }
        }
        u32 myPk[4];
        #pragma unroll
        for (int q = 0; q < 4; ++q) {
            int r = t + q * 1024;
            u32 pix = 0xFFFFu - (u32)(sel[r] & 0xFFFFULL);
            stash[b * NN + r] = pix;
            myPk[q] = (pix << 12) | (u32)r;
        }
        __syncthreads();
        u32* arr = (u32*)sel;
        #pragma unroll
        for (int q = 0; q < 4; ++q) arr[t + q * 1024] = myPk[q];
        __syncthreads();
        for (int k = 2; k <= NN; k <<= 1) {           // bitonic asc (spatial)
            for (int j = k >> 1; j > 0; j >>= 1) {
                for (int i = t; i < NN; i += 1024) {
                    int l = i ^ j;
                    if (l > i) {
                        u32 a = arr[i], c = arr[l];
                        bool up = ((i & k) == 0);
                        if ((a > c) == up) { arr[i] = c; arr[l] = a; }
                    }
                }
                __syncthreads();
            }
        }
        #pragma unroll
        for (int q = 0; q < 4; ++q) { int j = t + q * 1024; pixSorted[b * NN + j] = arr[j]; }
    } else {
        const int b = blockIdx.x - 8;
        u32* arr = (u32*)sel;
        for (int n = t; n < NN; n += 1024) {
            float gx = pc[((size_t)b * NN + n) * 2 + 0];
            float gy = pc[((size_t)b * NN + n) * 2 + 1];
            float fx = gx * 256.0f - 0.5f;
            float fy = gy * 256.0f - 0.5f;
            int x0 = (int)floorf(fx), y0 = (int)floorf(fy);
            int xc = min(max(x0, 0), 255), yc = min(max(y0, 0), 255);
            arr[n] = ((u32)(yc * 256 + xc) << 12) | (u32)n;
        }
        __syncthreads();
        for (int k = 2; k <= NN; k <<= 1) {
            for (int j = k >> 1; j > 0; j >>= 1) {
                for (int i = t; i < NN; i += 1024) {
                    int l = i ^ j;
                    if (l > i) {
                        u32 a = arr[i], c = arr[l];
                        bool up = ((i & k) == 0);
                        if ((a > c) == up) { arr[i] = c; arr[l] = a; }
                    }
                }
                __syncthreads();
            }
        }
        for (int n = t; n < NN; n += 1024) pcSorted[b * NN + n] = arr[n];
    }
}

// ---------------------------------------------------------------------------
// Per-point decoded parameters. Offsets are LDS offsets into the staged band.
struct LP { int o0, o1, o2; float w0, w1, w2, w3, wr2, invc; u32 rank; int v; };
struct SP { int o0, o1; float wv0, wv1, wr0, wr1; u32 n; int v; };

__device__ __forceinline__ LP decodeL(u32 packed, int rStart) {
    LP r;
    u32 pix = packed >> 12;
    r.rank = packed & 0xFFFu;
    int yi = (int)(pix >> 8), xi = (int)(pix & 255u);
    // replicate the reference float pipeline exactly (div, mul, int trunc)
    float cy = (float)yi / 255.0f, cx = (float)xi / 255.0f;
    int x = (int)(cx * 255.0f), y = (int)(cy * 255.0f);
    int x_min = max(x - 1, 0), x_max = min(x + 2, WW);
    int y_min = max(y - 1, 0), y_max = min(y + 2, HH);
    int xb = min(x_min, WW - 4);
    r.w0 = (xb + 0 >= x_min && xb + 0 < x_max) ? 1.0f : 0.0f;
    r.w1 = (xb + 1 >= x_min && xb + 1 < x_max) ? 1.0f : 0.0f;
    r.w2 = (xb + 2 >= x_min && xb + 2 < x_max) ? 1.0f : 0.0f;
    r.w3 = (xb + 3 >= x_min && xb + 3 < x_max) ? 1.0f : 0.0f;
    r.wr2 = (y_min + 2 < y_max) ? 1.0f : 0.0f;
    r.o0 = (y_min - rStart) * 256 + xb;
    r.o1 = r.o0 + 256;
    r.o2 = (min(y_min + 2, HH - 1) - rStart) * 256 + xb;
    r.invc = 1.0f / (float)((x_max - x_min) * (y_max - y_min));
    r.v = 1;
    return r;
}

__device__ __forceinline__ SP decodeS(u32 packed, const float* __restrict__ pcb, int rStart) {
    SP r;
    r.n = packed & 0xFFFu;
    float gx = pcb[2 * r.n + 0], gy = pcb[2 * r.n + 1];
    float fx = gx * 256.0f - 0.5f;   // power-of-2 mul: exact
    float fy = gy * 256.0f - 0.5f;
    float fx0 = floorf(fx), fy0 = floorf(fy);
    int x0 = (int)fx0, y0 = (int)fy0;
    float wx = fx - fx0, wy = fy - fy0;
    int xb = min(max(x0, 0), WW - 2);
    if (x0 < 0)            { r.wv0 = wx;        r.wv1 = 0.0f; }
    else if (x0 >= WW - 1) { r.wv0 = 0.0f;      r.wv1 = 1.0f - wx; }
    else                   { r.wv0 = 1.0f - wx; r.wv1 = wx; }
    r.wr0 = (y0 >= 0)     ? (1.0f - wy) : 0.0f;
    r.wr1 = (y0 + 1 < HH) ? wy          : 0.0f;
    int yc0 = min(max(y0, 0), HH - 1);
    int yc1 = min(max(y0 + 1, 0), HH - 1);
    r.o0 = (yc0 - rStart) * 256 + xb;
    r.o1 = (yc1 - rStart) * 256 + xb;
    r.v = 1;
    return r;
}

// ---------------------------------------------------------------------------
// K3: LDS-staged band-fused gather. Block = (band, 16-plane group, b).
// Each plane's 19-row band slice is staged with coalesced float4 loads
// (fm fetched coalesced, ~once); both point sets tap from LDS.
// 512-point chunks (2 per set per thread) -> one pass for this data.
template<int DO_L, int DO_S>
__global__ __launch_bounds__(256) void fused_gather_k(const float* __restrict__ fm,
                                                      const float* __restrict__ pc,
                                                      const u32* __restrict__ pixSorted,
                                                      const u32* __restrict__ pcSorted,
                                                      float* __restrict__ outLp,
                                                      float* __restrict__ outS) {
    __shared__ float sm[SROWS * 256];
    const int b = blockIdx.z, c0 = blockIdx.y * CG, band = blockIdx.x;
    const int t = threadIdx.x;
    const int rStart = band * 16 - 2;
    const u32 keyLo = (u32)band << 24, keyHi = (u32)(band + 1) << 24;
    u32 loL = 0, cL = 0, loS = 0, cS = 0;
    if (DO_L) {
        const u32* a = pixSorted + b * NN;
        loL = lbound(a, NN, keyLo); cL = lbound(a, NN, keyHi) - loL;
    }
    if (DO_S) {
        const u32* a = pcSorted + b * NN;
        loS = lbound(a, NN, keyLo); cS = lbound(a, NN, keyHi) - loS;
    }
    u32 cMax = cL > cS ? cL : cS;
    u32 iters = (cMax + 511) >> 9;
    const float* planes = fm + ((size_t)b * CC + c0) * HWV;
    const float* pcb = pc + (size_t)b * NN * 2;

    for (u32 it = 0; it < iters; ++it) {
        LP lp[2]; SP sp[2];
        float vL[2][CG]; float vS[2][CG];
        #pragma unroll
        for (int q = 0; q < 2; ++q) {
            lp[q].v = 0; lp[q].o0 = lp[q].o1 = lp[q].o2 = 0;
            lp[q].w0 = lp[q].w1 = lp[q].w2 = lp[q].w3 = lp[q].wr2 = lp[q].invc = 0.0f;
            lp[q].rank = 0;
            sp[q].v = 0; sp[q].o0 = sp[q].o1 = 0;
            sp[q].wv0 = sp[q].wv1 = sp[q].wr0 = sp[q].wr1 = 0.0f; sp[q].n = 0;
            if (DO_L) {
                u32 jl = it * 512 + (u32)t + (u32)q * 256;
                if (jl < cL) lp[q] = decodeL(pixSorted[b * NN + loL + jl], rStart);
            }
            if (DO_S) {
                u32 js = it * 512 + (u32)t + (u32)q * 256;
                if (js < cS) sp[q] = decodeS(pcSorted[b * NN + loS + js], pcb, rStart);
            }
        }
        #pragma unroll
        for (int j = 0; j < CG; ++j) {
            __syncthreads();   // protect prior plane's reads before overwrite
            {
                const float4* src = (const float4*)(planes + (size_t)j * HWV);
                float4* dst = (float4*)sm;
                #pragma unroll
                for (int u = 0; u < 5; ++u) {
                    int idx = t + u * 256;
                    if (idx < SROWS * 64) {
                        int r = idx >> 6, c4 = idx & 63;
                        int gr = rStart + r;
                        if (gr >= 0 && gr < HH) dst[idx] = src[gr * 64 + c4];
                    }
                }
            }
            __syncthreads();
            if (DO_L) {
                #pragma unroll
                for (int q = 0; q < 2; ++q) {
                    float s0 = sm[lp[q].o0] * lp[q].w0 + sm[lp[q].o0 + 1] * lp[q].w1
                             + sm[lp[q].o0 + 2] * lp[q].w2 + sm[lp[q].o0 + 3] * lp[q].w3;
                    float s1 = sm[lp[q].o1] * lp[q].w0 + sm[lp[q].o1 + 1] * lp[q].w1
                             + sm[lp[q].o1 + 2] * lp[q].w2 + sm[lp[q].o1 + 3] * lp[q].w3;
                    float s2 = sm[lp[q].o2] * lp[q].w0 + sm[lp[q].o2 + 1] * lp[q].w1
                             + sm[lp[q].o2 + 2] * lp[q].w2 + sm[lp[q].o2 + 3] * lp[q].w3;
                    vL[q][j] = (s0 + s1 + lp[q].wr2 * s2) * lp[q].invc;
                }
            }
            if (DO_S) {
                #pragma unroll
                for (int q = 0; q < 2; ++q) {
                    vS[q][j] = sp[q].wr0 * (sm[sp[q].o0] * sp[q].wv0 + sm[sp[q].o0 + 1] * sp[q].wv1)
                             + sp[q].wr1 * (sm[sp[q].o1] * sp[q].wv0 + sm[sp[q].o1 + 1] * sp[q].wv1);
                }
            }
        }
        // write phase: 64B contiguous per point
        if (DO_L) {
            #pragma unroll
            for (int q = 0; q < 2; ++q) if (lp[q].v) {
                float4* d = (float4*)(outLp + ((size_t)b * NN + lp[q].rank) * CC + c0);
                #pragma unroll
                for (int u = 0; u < 4; ++u)
                    d[u] = make_float4(vL[q][4 * u], vL[q][4 * u + 1], vL[q][4 * u + 2], vL[q][4 * u + 3]);
            }
        }
        if (DO_S) {
            #pragma unroll
            for (int q = 0; q < 2; ++q) if (sp[q].v) {
                float4* d = (float4*)(outS + ((size_t)b * NN + sp[q].n) * CC + c0);
                #pragma unroll
                for (int u = 0; u < 4; ++u)
                    d[u] = make_float4(vS[q][4 * u], vS[q][4 * u + 1], vS[q][4 * u + 2], vS[q][4 * u + 3]);
            }
        }
        __syncthreads();
    }
}

// ---------------------------------------------------------------------------
// K4: plain tile transpose outLp[b][r][c] -> outL[b][c][r].
__global__ __launch_bounds__(256) void transpose_k(const float* __restrict__ outLp,
                                                   float* __restrict__ outL) {
    __shared__ float tile[256][33];
    const int b = blockIdx.z, c0 = blockIdx.y * 32, r0 = blockIdx.x * 256;
    const int t = threadIdx.x;
    for (int idx = t; idx < 8192; idx += 256) {
        int p = idx >> 5, k = idx & 31;
        tile[p][k] = outLp[((size_t)b * NN + r0 + p) * CC + c0 + k];
    }
    __syncthreads();
    for (int idx = t; idx < 8192; idx += 256) {
        int cl = idx >> 8, col = idx & 255;
        outL[((size_t)b * CC + c0 + cl) * NN + r0 + col] = tile[col][cl];
    }
}

// ---------------------------------------------------------------------------
// K5 (LAST): coords (seg2) + idx (seg3) from the rank-order stash.
__global__ void emit_k(const u32* __restrict__ stash, float* __restrict__ outCoord,
                       float* __restrict__ outIdx) {
    int i = blockIdx.x * blockDim.x + threadIdx.x;   // 0..32767
    u32 p = stash[i];
    u32 yi = p >> 8, xi = p & 255u;
    outCoord[(size_t)i * 2 + 0] = (float)yi / 255.0f;
    outCoord[(size_t)i * 2 + 1] = (float)xi / 255.0f;
    outIdx[i] = (float)p;   // exact: p < 2^24
}

extern "C" void kernel_launch(void* const* d_in, const int* in_sizes, int n_in,
                              void* d_out, int out_size, void* d_ws, size_t ws_size,
                              hipStream_t stream) {
    const float* fm = (const float*)d_in[0];   // (8,256,256,256) f32
    const float* pm = (const float*)d_in[1];   // (8,1,256,256) f32
    const int*   em = (const int*)d_in[2];     // (8,256,256) i32
    const float* pc = (const float*)d_in[3];   // (8,4096,2) f32
    (void)in_sizes; (void)n_in; (void)out_size;

    float* out      = (float*)d_out;
    float* outL     = out;                         // local_feats (8,256,4096)
    float* outS     = out + (size_t)8388608;       // sampled     (8,4096,256)
    float* outCoord = out + (size_t)16777216;      // coords      (8,4096,2)
    float* outIdx   = out + (size_t)16842752;      // idx         (8,4096)

    const size_t need_ws = (size_t)40 * 1024 * 1024;
    bool ws_ok = ws_size >= need_ws;

    u64* keys; u32 *stash, *pixSorted, *pcSorted; float* outLp;
    if (ws_ok) {
        char* w = (char*)d_ws;
        keys      = (u64*)w;                       // 4 MB
        stash     = (u32*)(w + (size_t)4  * 1024 * 1024);   // 128 KB
        pixSorted = (u32*)(w + (size_t)4300 * 1024);        // 128 KB
        pcSorted  = (u32*)(w + (size_t)4600 * 1024);        // 128 KB
        outLp     = (float*)(w + (size_t)5 * 1024 * 1024);  // 33.5 MB
    } else {
        // alias scheme: keys/outLp in seg1 (seg1's final writer = fused<0,1>),
        // pixSorted/pcSorted in seg2, stash in seg3 (emit = final writer).
        keys      = (u64*)outS;
        stash     = (u32*)outIdx;
        pixSorted = (u32*)outCoord;
        pcSorted  = pixSorted + 32768;
        outLp     = outS;
    }

    hipLaunchKernelGGL(build_keys_k,  dim3(2048), dim3(256),  0, stream, pm, em, keys);
    hipLaunchKernelGGL(topk_sortpc_k, dim3(16),   dim3(1024), 0, stream, keys, pc, stash, pixSorted, pcSorted);
    if (ws_ok) {
        hipLaunchKernelGGL((fused_gather_k<1, 1>), dim3(16, CC / CG, 8), dim3(256), 0, stream,
                           fm, pc, pixSorted, pcSorted, outLp, outS);
        hipLaunchKernelGGL(transpose_k, dim3(16, 8, 8), dim3(256), 0, stream, outLp, outL);
    } else {
        hipLaunchKernelGGL((fused_gather_k<1, 0>), dim3(16, CC / CG, 8), dim3(256), 0, stream,
                           fm, pc, pixSorted, pcSorted, outLp, outS);
        hipLaunchKernelGGL(transpose_k, dim3(16, 8, 8), dim3(256), 0, stream, outLp, outL);
        hipLaunchKernelGGL((fused_gather_k<0, 1>), dim3(16, CC / CG, 8), dim3(256), 0, stream,
                           fm, pc, pixSorted, pcSorted, outS, outS);
    }
    hipLaunchKernelGGL(emit_k, dim3(128), dim3(256), 0, stream, stash, outCoord, outIdx);
}

// Round 9
// 321.558 us; speedup vs baseline: 2.8387x; 2.8387x over previous
//
#include <hip/hip_runtime.h>

#define CC 256
#define HH 256
#define WW 256
#define HWV 65536
#define NN 4096

using u64 = unsigned long long;
using u32 = unsigned int;

// ---------------------------------------------------------------------------
// K1: 48-bit sortable keys: (monotone(float) << 16) | (0xFFFF - pix).
// Distinct per pixel; descending key order == lax.top_k order.
__global__ void build_keys_k(const float* __restrict__ pm, const int* __restrict__ em,
                             u64* __restrict__ keys) {
    int i = blockIdx.x * blockDim.x + threadIdx.x;   // b*65536 + pix
    float f = (em[i] == 1) ? -fabsf(pm[i]) : -1e30f;
    u32 u = __float_as_uint(f);
    u32 k = (u & 0x80000000u) ? ~u : (u | 0x80000000u);
    u32 pix = (u32)i & 0xFFFFu;
    keys[i] = ((u64)k << 16) | (u64)(0xFFFFu - pix);
}

// ---------------------------------------------------------------------------
// K2: blocks 0-7 = per-batch exact top-k: 4x12-bit radix select + ONE desc
// bitonic (ranks) + bitmap/popcount spatial emit (replaces 2nd bitonic).
// blocks 8-15 = row counting-sort of point_coords (locality permutation only).
__global__ __launch_bounds__(1024) void topk_sortpc_k(const u64* __restrict__ keys,
                                                      const float* __restrict__ pc,
                                                      u32* __restrict__ stash,
                                                      u32* __restrict__ pixSorted,
                                                      u32* __restrict__ pcSorted) {
    __shared__ u64 sel[NN];      // 32 KB (phase1 aliases first 16KB as hist[4096])
    __shared__ u64 bm[1024];     // 8 KB bitmap / type-B: u32 counters
    __shared__ u32 wp[1024];     // 4 KB word-prefix / type-B: hist256
    __shared__ u32 s_digit, s_rem, s_cnt;
    const int t = threadIdx.x;
    if (blockIdx.x < 8) {
        const int b = blockIdx.x;
        const u64* kb = keys + (size_t)b * HWV;
        u32* hist = (u32*)sel;   // 4096 bins
        u64 prefix = 0ULL;
        u32 remaining = NN;
        for (int r = 0; r < 4; ++r) {
            int shift = 36 - 12 * r;
            #pragma unroll
            for (int q = 0; q < 4; ++q) hist[t + q * 1024] = 0u;
            __syncthreads();
            for (int i = t; i < HWV; i += 1024) {
                u64 K = kb[i];
                if ((K >> (shift + 12)) == prefix)
                    atomicAdd(&hist[(u32)((K >> shift) & 0xFFFULL)], 1u);
            }
            __syncthreads();
            // in-place suffix sum over 4096 bins
            for (int off = 1; off < 4096; off <<= 1) {
                u32 v[4];
                #pragma unroll
                for (int q = 0; q < 4; ++q) {
                    int i = t + q * 1024;
                    v[q] = hist[i];
                    if (i + off < 4096) v[q] += hist[i + off];
                }
                __syncthreads();
                #pragma unroll
                for (int q = 0; q < 4; ++q) hist[t + q * 1024] = v[q];
                __syncthreads();
            }
            #pragma unroll
            for (int q = 0; q < 4; ++q) {
                int d = t + q * 1024;
                u32 ge = hist[d];
                u32 gt = (d < 4095) ? hist[d + 1] : 0u;
                if (ge >= remaining && gt < remaining) { s_digit = (u32)d; s_rem = remaining - gt; }
            }
            __syncthreads();
            prefix = (prefix << 12) | (u64)s_digit;
            remaining = s_rem;
            __syncthreads();
        }
        // compaction: exactly 4096 keys satisfy K >= prefix (keys distinct)
        if (t == 0) s_cnt = 0u;
        __syncthreads();
        for (int i = t; i < HWV; i += 1024) {
            u64 K = kb[i];
            if (K >= prefix) { u32 p = atomicAdd(&s_cnt, 1u); sel[p] = K; }
        }
        __syncthreads();
        // descending bitonic sort (ranks; desc value, asc pixel on ties)
        for (int k = 2; k <= NN; k <<= 1) {
            for (int j = k >> 1; j > 0; j >>= 1) {
                for (int i = t; i < NN; i += 1024) {
                    int l = i ^ j;
                    if (l > i) {
                        u64 a = sel[i], c = sel[l];
                        bool asc = ((i & k) == 0);
                        if ((a < c) == asc) { sel[i] = c; sel[l] = a; }
                    }
                }
                __syncthreads();
            }
        }
        // stash (rank order) + bitmap of selected pixels
        bm[t] = 0ULL;
        __syncthreads();
        #pragma unroll
        for (int q = 0; q < 4; ++q) {
            int r = t + q * 1024;
            u32 pix = 0xFFFFu - (u32)(sel[r] & 0xFFFFULL);
            stash[b * NN + r] = pix;
            atomicOr(&bm[pix >> 6], 1ULL << (pix & 63));
        }
        __syncthreads();
        wp[t] = (u32)__popcll(bm[t]);
        __syncthreads();
        for (int off = 1; off < 1024; off <<= 1) {   // inclusive scan
            u32 v = wp[t];
            if (t >= off) v += wp[t - off];
            __syncthreads();
            wp[t] = v;
            __syncthreads();
        }
        // emit spatial order: pos = #selected pixels < pix (exact, == asc sort)
        #pragma unroll
        for (int q = 0; q < 4; ++q) {
            int r = t + q * 1024;
            u32 pix = 0xFFFFu - (u32)(sel[r] & 0xFFFFULL);
            int w = (int)(pix >> 6);
            u32 pos = wp[w] - (u32)__popcll(bm[w])
                    + (u32)__popcll(bm[w] & ((1ULL << (pix & 63)) - 1ULL));
            pixSorted[b * NN + pos] = (pix << 12) | (u32)r;
        }
    } else {
        // row counting-sort of pc (any within-row order is locality-equivalent)
        const int b = blockIdx.x - 8;
        u32* cellArr = (u32*)sel;    // 4096 u32
        u32* hist256 = wp;           // 256 bins
        u32* cnt     = (u32*)bm;     // 256 running counters
        if (t < 256) { hist256[t] = 0u; cnt[t] = 0u; }
        __syncthreads();
        for (int n = t; n < NN; n += 1024) {
            float gx = pc[((size_t)b * NN + n) * 2 + 0];
            float gy = pc[((size_t)b * NN + n) * 2 + 1];
            float fx = gx * 256.0f - 0.5f;
            float fy = gy * 256.0f - 0.5f;
            int x0 = (int)floorf(fx), y0 = (int)floorf(fy);
            int xc = min(max(x0, 0), 255), yc = min(max(y0, 0), 255);
            cellArr[n] = ((u32)(yc * 256 + xc) << 12) | (u32)n;
            atomicAdd(&hist256[yc], 1u);
        }
        __syncthreads();
        for (int off = 1; off < 256; off <<= 1) {    // inclusive scan over 256
            u32 v = 0;
            if (t < 256) { v = hist256[t]; if (t >= off) v += hist256[t - off]; }
            __syncthreads();
            if (t < 256) hist256[t] = v;
            __syncthreads();
        }
        for (int n = t; n < NN; n += 1024) {
            u32 pk = cellArr[n];
            u32 yc = pk >> 20;
            u32 base = (yc > 0) ? hist256[yc - 1] : 0u;
            u32 pos = base + atomicAdd(&cnt[yc], 1u);
            pcSorted[b * NN + pos] = pk;
        }
    }
}

// ---------------------------------------------------------------------------
// K3: merged gather. MODE 0: y<8 -> local-gather cgroup y, y>=8 -> sample
// cgroup y-8 (co-resident partner blocks share fm bands via L2/L3).
// MODE 1: local only. MODE 2: sample only. Bodies = round-6 proven kernels.
template<int MODE>
__global__ __launch_bounds__(256) void gather_k(const float* __restrict__ fm,
                                                const float* __restrict__ pc,
                                                const u32* __restrict__ pixSorted,
                                                const u32* __restrict__ pcSorted,
                                                float* __restrict__ outLp,
                                                float* __restrict__ outS) {
    __shared__ float tile[256][33];
    __shared__ u32 pidx[256];
    const int b = blockIdx.z, j0 = blockIdx.x * 256, t = threadIdx.x;
    bool doL; int c0;
    if (MODE == 0) { doL = (blockIdx.y < 8); c0 = (doL ? blockIdx.y : blockIdx.y - 8) * 32; }
    else if (MODE == 1) { doL = true; c0 = blockIdx.y * 32; }
    else { doL = false; c0 = blockIdx.y * 32; }
    const float* planes = fm + ((size_t)b * CC + c0) * HWV;

    if (doL) {
        u32 packed = pixSorted[b * NN + j0 + t];
        u32 pix = packed >> 12;
        pidx[t] = packed & 0xFFFu;
        int yi = (int)(pix >> 8), xi = (int)(pix & 255u);
        // replicate the reference float pipeline exactly (div, mul, int trunc)
        float cy = (float)yi / 255.0f;
        float cx = (float)xi / 255.0f;
        int x = (int)(cx * 255.0f);
        int y = (int)(cy * 255.0f);
        int x_min = max(x - 1, 0), x_max = min(x + 2, WW);
        int y_min = max(y - 1, 0), y_max = min(y + 2, HH);
        int xb = min(x_min, WW - 4);
        float w0 = (xb + 0 >= x_min && xb + 0 < x_max) ? 1.0f : 0.0f;
        float w1 = (xb + 1 >= x_min && xb + 1 < x_max) ? 1.0f : 0.0f;
        float w2 = (xb + 2 >= x_min && xb + 2 < x_max) ? 1.0f : 0.0f;
        float w3 = (xb + 3 >= x_min && xb + 3 < x_max) ? 1.0f : 0.0f;
        float wr2 = (y_min + 2 < y_max) ? 1.0f : 0.0f;
        int o0 = y_min * WW + xb;
        int o1 = o0 + WW;
        int o2 = min(y_min + 2, HH - 1) * WW + xb;
        float invc = 1.0f / (float)((x_max - x_min) * (y_max - y_min));
        #pragma unroll 4
        for (int j = 0; j < 32; ++j) {
            const float* p = planes + (size_t)j * HWV;
            float s0 = p[o0] * w0 + p[o0 + 1] * w1 + p[o0 + 2] * w2 + p[o0 + 3] * w3;
            float s1 = p[o1] * w0 + p[o1 + 1] * w1 + p[o1 + 2] * w2 + p[o1 + 3] * w3;
            float s2 = p[o2] * w0 + p[o2 + 1] * w1 + p[o2 + 2] * w2 + p[o2 + 3] * w3;
            tile[t][j] = (s0 + s1 + wr2 * s2) * invc;
        }
        __syncthreads();
        for (int idx = t; idx < 8192; idx += 256) {
            int p = idx >> 5, k = idx & 31;
            outLp[((size_t)b * NN + pidx[p]) * CC + c0 + k] = tile[p][k];
        }
    } else {
        int n = (int)(pcSorted[b * NN + j0 + t] & 0xFFFu);
        pidx[t] = (u32)n;
        float gx = pc[((size_t)b * NN + n) * 2 + 0];
        float gy = pc[((size_t)b * NN + n) * 2 + 1];
        float fx = gx * 256.0f - 0.5f;   // power-of-2 mul: exact
        float fy = gy * 256.0f - 0.5f;
        float fx0 = floorf(fx), fy0 = floorf(fy);
        int x0 = (int)fx0, y0 = (int)fy0;       // in [-1, 255]
        float wx = fx - fx0, wy = fy - fy0;
        int xb = min(max(x0, 0), WW - 2);
        float wv0, wv1;
        if (x0 < 0)            { wv0 = wx;        wv1 = 0.0f; }
        else if (x0 >= WW - 1) { wv0 = 0.0f;      wv1 = 1.0f - wx; }
        else                   { wv0 = 1.0f - wx; wv1 = wx; }
        float wr0 = (y0 >= 0)     ? (1.0f - wy) : 0.0f;
        float wr1 = (y0 + 1 < HH) ? wy          : 0.0f;
        int yc0 = min(max(y0, 0), HH - 1);
        int yc1 = min(max(y0 + 1, 0), HH - 1);
        int o0 = yc0 * WW + xb;
        int o1 = yc1 * WW + xb;
        #pragma unroll 4
        for (int j = 0; j < 32; ++j) {
            const float* p = planes + (size_t)j * HWV;
            tile[t][j] = wr0 * (p[o0] * wv0 + p[o0 + 1] * wv1)
                       + wr1 * (p[o1] * wv0 + p[o1 + 1] * wv1);
        }
        __syncthreads();
        for (int idx = t; idx < 8192; idx += 256) {
            int p = idx >> 5, k = idx & 31;
            outS[((size_t)b * NN + pidx[p]) * CC + c0 + k] = tile[p][k];
        }
    }
}

// ---------------------------------------------------------------------------
// K4: plain tile transpose outLp[b][r][c] -> outL[b][c][r].
__global__ __launch_bounds__(256) void transpose_k(const float* __restrict__ outLp,
                                                   float* __restrict__ outL) {
    __shared__ float tile[256][33];
    const int b = blockIdx.z, c0 = blockIdx.y * 32, r0 = blockIdx.x * 256;
    const int t = threadIdx.x;
    for (int idx = t; idx < 8192; idx += 256) {
        int p = idx >> 5, k = idx & 31;
        tile[p][k] = outLp[((size_t)b * NN + r0 + p) * CC + c0 + k];
    }
    __syncthreads();
    for (int idx = t; idx < 8192; idx += 256) {
        int cl = idx >> 8, col = idx & 255;
        outL[((size_t)b * CC + c0 + cl) * NN + r0 + col] = tile[col][cl];
    }
}

// ---------------------------------------------------------------------------
// K5 (LAST): coords (seg2) + idx (seg3) from the rank-order stash.
__global__ void emit_k(const u32* __restrict__ stash, float* __restrict__ outCoord,
                       float* __restrict__ outIdx) {
    int i = blockIdx.x * blockDim.x + threadIdx.x;   // 0..32767
    u32 p = stash[i];
    u32 yi = p >> 8, xi = p & 255u;
    outCoord[(size_t)i * 2 + 0] = (float)yi / 255.0f;
    outCoord[(size_t)i * 2 + 1] = (float)xi / 255.0f;
    outIdx[i] = (float)p;   // exact: p < 2^24
}

extern "C" void kernel_launch(void* const* d_in, const int* in_sizes, int n_in,
                              void* d_out, int out_size, void* d_ws, size_t ws_size,
                              hipStream_t stream) {
    const float* fm = (const float*)d_in[0];   // (8,256,256,256) f32
    const float* pm = (const float*)d_in[1];   // (8,1,256,256) f32
    const int*   em = (const int*)d_in[2];     // (8,256,256) i32
    const float* pc = (const float*)d_in[3];   // (8,4096,2) f32
    (void)in_sizes; (void)n_in; (void)out_size;

    float* out      = (float*)d_out;
    float* outL     = out;                         // local_feats (8,256,4096)
    float* outS     = out + (size_t)8388608;       // sampled     (8,4096,256)
    float* outCoord = out + (size_t)16777216;      // coords      (8,4096,2)
    float* outIdx   = out + (size_t)16842752;      // idx         (8,4096)

    const size_t need_ws = (size_t)40 * 1024 * 1024;
    bool ws_ok = ws_size >= need_ws;

    u64* keys; u32 *stash, *pixSorted, *pcSorted; float* outLp;
    if (ws_ok) {
        char* w = (char*)d_ws;
        keys      = (u64*)w;                                // 4 MB
        stash     = (u32*)(w + (size_t)4  * 1024 * 1024);   // 128 KB
        pixSorted = (u32*)(w + (size_t)4300 * 1024);        // 128 KB
        pcSorted  = (u32*)(w + (size_t)4600 * 1024);        // 128 KB
        outLp     = (float*)(w + (size_t)5 * 1024 * 1024);  // 33.5 MB
    } else {
        // alias scheme: keys/outLp in seg1 (final writer = gather<2>),
        // pixSorted/pcSorted in seg2 (final writer = emit), stash in seg3.
        keys      = (u64*)outS;
        stash     = (u32*)outIdx;
        pixSorted = (u32*)outCoord;
        pcSorted  = pixSorted + 32768;
        outLp     = outS;
    }

    hipLaunchKernelGGL(build_keys_k,  dim3(2048), dim3(256),  0, stream, pm, em, keys);
    hipLaunchKernelGGL(topk_sortpc_k, dim3(16),   dim3(1024), 0, stream, keys, pc, stash, pixSorted, pcSorted);
    if (ws_ok) {
        hipLaunchKernelGGL((gather_k<0>), dim3(16, 16, 8), dim3(256), 0, stream,
                           fm, pc, pixSorted, pcSorted, outLp, outS);
        hipLaunchKernelGGL(transpose_k, dim3(16, 8, 8), dim3(256), 0, stream, outLp, outL);
    } else {
        hipLaunchKernelGGL((gather_k<1>), dim3(16, 8, 8), dim3(256), 0, stream,
                           fm, pc, pixSorted, pcSorted, outLp, outS);
        hipLaunchKernelGGL(transpose_k, dim3(16, 8, 8), dim3(256), 0, stream, outLp, outL);
        hipLaunchKernelGGL((gather_k<2>), dim3(16, 8, 8), dim3(256), 0, stream,
                           fm, pc, pixSorted, pcSorted, outS, outS);
    }
    hipLaunchKernelGGL(emit_k, dim3(128), dim3(256), 0, stream, stash, outCoord, outIdx);
}